// Round 11
// baseline (126.964 us; speedup 1.0000x reference)
//
#include <hip/hip_runtime.h>
#include <math.h>

#define B_ROWS 4096
#define T_COLS 4096
#define NTHREADS 256
#define WPB 4                     // 4 waves per block, one ROW per WAVE (no barriers)
#define NBLOCKS (B_ROWS / WPB)    // 1024 blocks = 4/CU resident = 16 waves/CU
#define NSTRIPE 8                 // 8 stripes of 512 elements; 8 elems (2 float4) per lane

// Force a (wave-uniform) float into an SGPR.
__device__ __forceinline__ float rfl(float v) {
    return __int_as_float(__builtin_amdgcn_readfirstlane(__float_as_int(v)));
}

#define STEP(z, xv) fmaf(beta, (z), fmaf(alpha, (xv) * (xv), omega))
#define SQ(z) __builtin_amdgcn_sqrtf(z)

__global__ __launch_bounds__(NTHREADS, 4) void garch_fused(
    const float* __restrict__ x,
    const float* __restrict__ p_omega_log,
    const float* __restrict__ p_alpha_log,
    const float* __restrict__ p_beta_log,
    float* __restrict__ out)
{
    const int lane = threadIdx.x & 63;
    const int wv   = threadIdx.x >> 6;
    const long row = (long)blockIdx.x * WPB + wv;

    const float4* X4 = reinterpret_cast<const float4*>(x + row * T_COLS);
    float4*       O4 = reinterpret_cast<float4*>(out + row * T_COLS);

    // ---- Uniform scalar parameter work -> SGPRs ----
    float ea_p  = expf(p_alpha_log[0]);
    float eb_p  = expf(p_beta_log[0]);
    float denom = 1.0f + ea_p + eb_p;
    float omega = rfl(expf(p_omega_log[0]));
    float alpha = rfl(ea_p / denom);
    float beta  = rfl(eb_p / denom);

    // Powers of beta for the constant-coefficient scan ladder.
    float beta2 = beta * beta;
    float beta4 = beta2 * beta2;
    float beta7 = beta4 * beta2 * beta;
    float c1  = beta4 * beta4;    // beta^8
    float c2  = c1  * c1;         // beta^16
    float c4  = c2  * c2;         // beta^32
    float c8  = c4  * c4;         // beta^64
    float c16 = c8  * c8;         // beta^128
    float c32 = c16 * c16;        // beta^256

    // blA = beta^(8*lane) via binary expansion of lane.
    float blA = (lane & 1)  ? c1  : 1.0f;
    if (lane & 2)  blA *= c2;
    if (lane & 4)  blA *= c4;
    if (lane & 8)  blA *= c8;
    if (lane & 16) blA *= c16;
    if (lane & 32) blA *= c32;
    const float Anorm = blA * c1;     // beta^(8*(lane+1)): exit coef, stripes >= 1
    const float Azero = blA * beta7;  // stripe 0: lane 0's segment has 7 steps

    // ================= PASS 1: variance (pure accumulator loop) ==============
    // 16 independent dwordx4 per lane feeding only accumulators: the compiler
    // pipelines this reduction idiom reliably (R5/R7 lesson: serial-chain
    // consumers de-pipeline loads; accumulators don't).
    float sum = 0.0f, ssq = 0.0f;
#pragma unroll
    for (int s = 0; s < 16; ++s) {
        float4 a = X4[64 * s + lane];
        sum += (a.x + a.y) + (a.z + a.w);
        ssq = fmaf(a.x, a.x, ssq); ssq = fmaf(a.y, a.y, ssq);
        ssq = fmaf(a.z, a.z, ssq); ssq = fmaf(a.w, a.w, ssq);
    }
#pragma unroll
    for (int d = 32; d > 0; d >>= 1) {
        sum += __shfl_xor(sum, d);
        ssq += __shfl_xor(ssq, d);
    }
    float s0 = (ssq - sum * sum * (1.0f / T_COLS)) * (1.0f / (T_COLS - 1));
    s0 = fmaxf(s0, 0.0f);

    // ================= PASS 2: striped scan + recompute + store ==============
    // Stripe s = elements [512s, 512s+512); lane owns 8 contiguous elements
    // (two float4s). One-deep prefetch keeps loads hoisted (R4/R8 idiom); the
    // only serial cross-stripe dependence is E (1 fma + 1 shfl per stripe).
    float E = s0;                 // sigma2 state entering the stripe
    float carryX = 0.0f;          // x[512s - 1], unused at s=0
    float4 a = X4[2 * lane];
    float4 b = X4[2 * lane + 1];
#pragma unroll
    for (int s = 0; s < NSTRIPE; ++s) {
        // Prefetch next stripe (consumed only next iteration -> stays hoisted).
        float4 an, bn;
        if (s + 1 < NSTRIPE) {
            const float4* Xn = X4 + 128 * (s + 1) + 2 * lane;
            an = Xn[0];
            bn = Xn[1];
        } else {
            an = a; bn = b;
        }

        // x[512s + 8*lane - 1]: lane-1's b.w, or the stripe carry for lane 0.
        float xm1 = __shfl_up(b.w, 1);
        if (lane == 0) xm1 = carryX;

        // Per-lane zero-init chain over the lane's 8 steps (7 for lane0/s0).
        float z0 = (s == 0 && lane == 0) ? fmaf(alpha, a.x * a.x, omega)
                                         : STEP(fmaf(alpha, xm1 * xm1, omega), a.x);
        z0 = STEP(z0, a.y); z0 = STEP(z0, a.z); z0 = STEP(z0, a.w);
        z0 = STEP(z0, b.x); z0 = STEP(z0, b.y); z0 = STEP(z0, b.z);
        float ib = z0;

        // Constant-coefficient inclusive scan of ib: every composing window
        // multiplies only by later lanes' uniform beta^8 decay, so the "ia"
        // half of the affine scan collapses to the precomputed c-ladder
        // (6 shfl + 6 fma; lane 0's irregular coef only enters via A below).
        float pb;
        pb = __shfl_up(ib, 1);  if (lane >= 1)  ib = fmaf(c1,  pb, ib);
        pb = __shfl_up(ib, 2);  if (lane >= 2)  ib = fmaf(c2,  pb, ib);
        pb = __shfl_up(ib, 4);  if (lane >= 4)  ib = fmaf(c4,  pb, ib);
        pb = __shfl_up(ib, 8);  if (lane >= 8)  ib = fmaf(c8,  pb, ib);
        pb = __shfl_up(ib, 16); if (lane >= 16) ib = fmaf(c16, pb, ib);
        pb = __shfl_up(ib, 32); if (lane >= 32) ib = fmaf(c32, pb, ib);

        // exit = sigma2 at the last element of this lane's segment.
        float A  = (s == 0) ? Azero : Anorm;
        float ex = fmaf(A, E, ib);
        float e  = __shfl_up(ex, 1);      // entry = exit of lane-1
        if (lane == 0) e = E;
        float Enext = __shfl(ex, 63);
        float carryN = __shfl(b.w, 63);

        // Recompute 8 outputs + sqrt, store coalesced.
        float4 q1, q2;
        float z = (s == 0 && lane == 0) ? e : STEP(e, xm1);   // out 0 = s0 itself
        q1.x = SQ(z);
        z = STEP(z, a.x); q1.y = SQ(z);
        z = STEP(z, a.y); q1.z = SQ(z);
        z = STEP(z, a.z); q1.w = SQ(z);
        z = STEP(z, a.w); q2.x = SQ(z);
        z = STEP(z, b.x); q2.y = SQ(z);
        z = STEP(z, b.y); q2.z = SQ(z);
        z = STEP(z, b.z); q2.w = SQ(z);
        float4* On = O4 + 128 * s + 2 * lane;
        On[0] = q1;
        On[1] = q2;

        // Cross-stripe carries.
        carryX = carryN;
        E = Enext;
        a = an; b = bn;
    }
}

extern "C" void kernel_launch(void* const* d_in, const int* in_sizes, int n_in,
                              void* d_out, int out_size, void* d_ws, size_t ws_size,
                              hipStream_t stream) {
    const float* x         = (const float*)d_in[0];
    const float* omega_log = (const float*)d_in[1];
    const float* alpha_log = (const float*)d_in[2];
    const float* beta_log  = (const float*)d_in[3];
    float* out = (float*)d_out;

    garch_fused<<<NBLOCKS, NTHREADS, 0, stream>>>(x, omega_log, alpha_log, beta_log, out);
}